// Round 2
// baseline (22157.385 us; speedup 1.0000x reference)
//
#include <hip/hip_runtime.h>

#define SLEN 512
#define BATCH 64
#define HID 256
#define EMB 128
#define NT 18
#define KTOT 384          // 256 (h) + 128 (emb)
#define BQ 16             // batches per group
#define WGS_PER_GROUP 32
#define FB 8              // batches per feats block

typedef unsigned int u32;

__device__ __forceinline__ float sigmoidf_(float v) { return 1.0f / (1.0f + expf(-v)); }

// ---------------------------------------------------------------------------
// Persistent bidirectional LSTM. grid = 256 blocks x 256 threads (1 WG/CU).
// group g = blockIdx%8 : dir = g>>2, batch-chunk = g&3 (16 batches).
// rank rk = blockIdx/8 : owns hidden units [8rk, 8rk+8) -> 32 gate rows.
// Weights live in VGPRs (8-way K-split, 48 floats/thread). Group barrier via
// agent-scope atomic counter per (group, step).
// ---------------------------------------------------------------------------
__global__ __launch_bounds__(256, 1) void lstm_kernel(
    const int* __restrict__ x, const float* __restrict__ embed,
    const float* __restrict__ Wih_f, const float* __restrict__ Whh_f,
    const float* __restrict__ bih_f, const float* __restrict__ bhh_f,
    const float* __restrict__ Wih_b, const float* __restrict__ Whh_b,
    const float* __restrict__ bih_b, const float* __restrict__ bhh_b,
    const float* __restrict__ h0, const float* __restrict__ c0,
    float* __restrict__ h_hist, u32* __restrict__ cnt)
{
  const int g   = blockIdx.x & 7;
  const int rk  = blockIdx.x >> 3;
  const int dir = g >> 2;
  const int b0  = (g & 3) * BQ;
  const int tid = threadIdx.x;
  const int kg  = tid >> 5;          // 0..7  (K-split group, 48 k's each)
  const int r   = tid & 31;          // row within WG's 32 gate rows
  const int gi  = r >> 3;            // gate index: 0=i 1=f 2=g 3=o
  const int uo  = r & 7;             // unit offset
  const int grow = gi * 256 + rk * 8 + uo;

  const float* Wih = dir ? Wih_b : Wih_f;
  const float* Whh = dir ? Whh_b : Whh_f;
  const float* bih = dir ? bih_b : bih_f;
  const float* bhh = dir ? bhh_b : bhh_f;

  // persistent weight slice: rows 'grow', k in [48*kg, 48*kg+48)
  float4 wreg[12];
#pragma unroll
  for (int c = 0; c < 12; ++c) {
    int k0 = kg * 48 + c * 4;
    if (k0 < 256) wreg[c] = *(const float4*)(Whh + (size_t)grow * 256 + k0);
    else          wreg[c] = *(const float4*)(Wih + (size_t)grow * 128 + (k0 - 256));
  }

  __shared__ float vlds[BQ][KTOT];   // v = [h_prev (256) | emb (128)]
  __shared__ float red[4][BQ][33];   // cross-wave partial reduction
  __shared__ float cst[BQ][8];       // cell state (persistent)
  __shared__ float bias[32];
  __shared__ int   xids[BQ];

  if (tid < 32) {
    int gr2 = (tid >> 3) * 256 + rk * 8 + (tid & 7);
    bias[tid] = bih[gr2] + bhh[gr2];
  }
  if (tid < 128) {
    int b = tid >> 3, u = tid & 7;
    cst[b][u] = c0[(size_t)(dir * BATCH + b0 + b) * HID + rk * 8 + u];
  }

  int spins = 0;
  for (int it = 0; it < SLEN; ++it) {
    const int t = dir ? (SLEN - 1 - it) : it;

    // ---- stage v into LDS ----
    if (tid < BQ) xids[tid] = x[(b0 + tid) * SLEN + t];
    const float* hsrc;
    if (it == 0) hsrc = h0 + (size_t)(dir * BATCH + b0) * HID;
    else {
      const int tp = dir ? (t + 1) : (t - 1);
      hsrc = h_hist + ((size_t)(dir * SLEN + tp) * BATCH + b0) * HID;
    }
#pragma unroll
    for (int f = tid * 4; f < BQ * HID; f += 1024) {
      float4 hv = *(const float4*)(hsrc + f);
      *(float4*)&vlds[f >> 8][f & 255] = hv;
    }
    __syncthreads();   // xids ready
#pragma unroll
    for (int f = tid * 4; f < BQ * EMB; f += 1024) {
      int b = f >> 7, e = f & 127;
      float4 ev = *(const float4*)(embed + (size_t)xids[b] * EMB + e);
      *(float4*)&vlds[b][256 + e] = ev;
    }
    __syncthreads();

    // ---- K-split GEMM: acc[b] = sum over this thread's 48 k's ----
    float acc[BQ];
#pragma unroll
    for (int b = 0; b < BQ; ++b) acc[b] = 0.0f;
    const int kb = kg * 48;
#pragma unroll
    for (int bb = 0; bb < BQ; bb += 4) {
#pragma unroll
      for (int c = 0; c < 12; ++c) {
        float4 w4 = wreg[c];
#pragma unroll
        for (int q = 0; q < 4; ++q) {
          float4 v4 = *(const float4*)&vlds[bb + q][kb + c * 4];
          float a = acc[bb + q];
          a = fmaf(w4.x, v4.x, a);
          a = fmaf(w4.y, v4.y, a);
          a = fmaf(w4.z, v4.z, a);
          a = fmaf(w4.w, v4.w, a);
          acc[bb + q] = a;
        }
      }
    }

    // ---- reduce the 8 K-partials: in-wave pair, then 4 waves via LDS ----
#pragma unroll
    for (int b = 0; b < BQ; ++b) acc[b] += __shfl_xor(acc[b], 32);
    const int wv = tid >> 6;
    if ((tid & 32) == 0) {
#pragma unroll
      for (int b = 0; b < BQ; ++b) red[wv][b][r] = acc[b];
    }
    __syncthreads();

    // ---- gates + state update + h write ----
    if (tid < 128) {
      int b = tid >> 3, u = tid & 7;
      float gs[4];
#pragma unroll
      for (int gg = 0; gg < 4; ++gg) {
        int rr = gg * 8 + u;
        float s = bias[rr];
#pragma unroll
        for (int w = 0; w < 4; ++w) s += red[w][b][rr];
        gs[gg] = s;
      }
      float ig = sigmoidf_(gs[0]);
      float fg = sigmoidf_(gs[1]);
      float gv = tanhf(gs[2]);
      float og = sigmoidf_(gs[3]);
      float cv = fg * cst[b][u] + ig * gv;
      cst[b][u] = cv;
      float hv = og * tanhf(cv);
      h_hist[((size_t)(dir * SLEN + t) * BATCH + (b0 + b)) * HID + rk * 8 + u] = hv;
    }

    // ---- group barrier (release h, wait for all 32 WGs, acquire) ----
    __threadfence();
    __syncthreads();
    if (tid == 0) {
      u32* c = cnt + (g * SLEN + it);
      __hip_atomic_fetch_add(c, 1u, __ATOMIC_RELEASE, __HIP_MEMORY_SCOPE_AGENT);
      while (__hip_atomic_load(c, __ATOMIC_ACQUIRE, __HIP_MEMORY_SCOPE_AGENT) < WGS_PER_GROUP) {
        if (++spins > (1 << 24)) break;   // deadlock insurance
      }
    }
    __syncthreads();
    __threadfence();
  }
}

// ---------------------------------------------------------------------------
// feats[s][b][tag] = [hf|hb] . Wc[tag] + bc[tag]
// grid = 512*8 blocks (s, 8-batch chunk), 256 threads. LDS ~54KB.
// ---------------------------------------------------------------------------
__global__ __launch_bounds__(256) void feats_kernel(
    const float* __restrict__ h_hist, const float* __restrict__ Wc,
    const float* __restrict__ bc, float* __restrict__ feats)
{
  const int s   = blockIdx.x >> 3;
  const int b0  = (blockIdx.x & 7) * FB;
  const int tid = threadIdx.x;
  __shared__ float wc[NT * 516];    // 37.2 KB
  __shared__ float hl[FB * 516];    // 16.5 KB
  __shared__ float bcl[NT];
  if (tid < NT) bcl[tid] = bc[tid];
  for (int f = tid * 4; f < NT * 512; f += 1024) {
    float4 v = *(const float4*)(Wc + f);
    *(float4*)&wc[(f >> 9) * 516 + (f & 511)] = v;
  }
  {
    const float* src0 = h_hist + ((size_t)s * BATCH + b0) * HID;
    const float* src1 = h_hist + ((size_t)(SLEN + s) * BATCH + b0) * HID;
    for (int f = tid * 4; f < FB * 256; f += 1024) {
      int b = f >> 8, j = f & 255;
      *(float4*)&hl[b * 516 + j]       = *(const float4*)(src0 + f);
      *(float4*)&hl[b * 516 + 256 + j] = *(const float4*)(src1 + f);
    }
  }
  __syncthreads();
  if (tid < FB * NT) {
    int b = tid / NT, tag = tid - b * NT;
    float a = bcl[tag];
    const float* hp = &hl[b * 516];
    const float* wp = &wc[tag * 516];
#pragma unroll 8
    for (int k = 0; k < 512; k += 4) {
      float4 h4 = *(const float4*)(hp + k);
      float4 w4 = *(const float4*)(wp + k);
      a = fmaf(h4.x, w4.x, a); a = fmaf(h4.y, w4.y, a);
      a = fmaf(h4.z, w4.z, a); a = fmaf(h4.w, w4.w, a);
    }
    feats[((size_t)s * BATCH + b0 + b) * NT + tag] = a;
  }
}

// ---------------------------------------------------------------------------
// Viterbi + backtrace, one block per batch, 64 threads (lanes 0..17 active).
// Replicates reference exactly, including add order:
//   cur = (feats[to] + trans[from][to]) + partition[from];  new_p = max(cur)
// strict > keeps the FIRST max (matches jnp.argmax). Masked bp=0, snapshot at
// t=len-1, back[len-1]=pointer overwrite, decode[S-1]=pointer.
// ---------------------------------------------------------------------------
__global__ __launch_bounds__(64) void viterbi_kernel(
    const float* __restrict__ feats, const int* __restrict__ mask,
    const float* __restrict__ trans, float* __restrict__ out)
{
  const int b = blockIdx.x;
  const int lane = threadIdx.x;
  __shared__ float tr[NT][NT + 1];
  __shared__ float part[2][NT + 2];
  __shared__ float lastp[NT + 2];
  __shared__ unsigned char bp[SLEN][20];
  __shared__ int len_s;

  for (int f = lane; f < NT * NT; f += 64) tr[f / NT][f % NT] = trans[f];
  int m = 0;
#pragma unroll
  for (int i = 0; i < 8; ++i) m += mask[b * SLEN + lane * 8 + i];
  for (int off = 32; off; off >>= 1) m += __shfl_down(m, off);
  if (lane == 0) len_s = m;
  __syncthreads();
  const int len = len_s;

  if (lane < NT) part[0][lane] = feats[(size_t)b * NT + lane] + tr[16][lane];  // START=16
  __syncthreads();

  int cur = 0;
  float fnext = (lane < NT) ? feats[((size_t)BATCH + b) * NT + lane] : 0.0f;
  int   mnext = mask[b * SLEN + 1];
  for (int t = 1; t < SLEN; ++t) {
    float fcur = fnext; int mcur = mnext;
    if (t < SLEN - 1) {
      fnext = (lane < NT) ? feats[((size_t)(t + 1) * BATCH + b) * NT + lane] : 0.0f;
      mnext = mask[b * SLEN + t + 1];
    }
    if (lane < NT) {
      float best = -3.0e38f; int bf = 0;
#pragma unroll
      for (int from = 0; from < NT; ++from) {
        float v = (fcur + tr[from][lane]) + part[cur][from];  // exact ref order
        if (v > best) { best = v; bf = from; }
      }
      part[cur ^ 1][lane] = best;          // new_p includes feats (ref semantics)
      bp[t][lane] = mcur ? (unsigned char)bf : (unsigned char)0;
      if (t == len - 1) lastp[lane] = best;
    }
    cur ^= 1;
    __syncthreads();
  }

  if (lane == 0) {
    float best = -3.0e38f; int bf = 0;
    for (int from = 0; from < NT; ++from) {
      float v = lastp[from] + tr[from][17];      // END=17
      if (v > best) { best = v; bf = from; }
    }
    out[b] = best;                                // path_score
    int ptr = bf;
    out[BATCH + (size_t)b * SLEN + (SLEN - 1)] = (float)ptr;
    for (int i = SLEN - 2; i >= 0; --i) {
      int nw = (i == len - 1) ? bf : (int)bp[i + 1][ptr];
      out[BATCH + (size_t)b * SLEN + i] = (float)nw;
      ptr = nw;
    }
  }
}

// ---------------------------------------------------------------------------
extern "C" void kernel_launch(void* const* d_in, const int* in_sizes, int n_in,
                              void* d_out, int out_size, void* d_ws, size_t ws_size,
                              hipStream_t stream) {
  const int*   x      = (const int*)  d_in[0];
  const int*   mask   = (const int*)  d_in[1];
  const float* embed  = (const float*)d_in[2];
  const float* Wih_f  = (const float*)d_in[3];
  const float* Whh_f  = (const float*)d_in[4];
  const float* bih_f  = (const float*)d_in[5];
  const float* bhh_f  = (const float*)d_in[6];
  const float* Wih_b  = (const float*)d_in[7];
  const float* Whh_b  = (const float*)d_in[8];
  const float* bih_b  = (const float*)d_in[9];
  const float* bhh_b  = (const float*)d_in[10];
  const float* Wc     = (const float*)d_in[11];
  const float* bc     = (const float*)d_in[12];
  const float* trans  = (const float*)d_in[13];
  const float* h0     = (const float*)d_in[14];
  const float* c0     = (const float*)d_in[15];
  float* out = (float*)d_out;

  char* ws = (char*)d_ws;
  u32*   cnt    = (u32*)ws;                                   // 8*512*4 = 16 KB
  float* h_hist = (float*)(ws + 16384);                       // 2*512*64*256*4 = 64 MB
  float* feats  = (float*)(ws + 16384 + (size_t)67108864);    // 512*64*18*4 = 2.25 MB

  hipMemsetAsync(cnt, 0, 8 * SLEN * sizeof(u32), stream);
  lstm_kernel<<<256, 256, 0, stream>>>(x, embed, Wih_f, Whh_f, bih_f, bhh_f,
                                       Wih_b, Whh_b, bih_b, bhh_b, h0, c0,
                                       h_hist, cnt);
  feats_kernel<<<SLEN * 8, 256, 0, stream>>>(h_hist, Wc, bc, feats);
  viterbi_kernel<<<BATCH, 64, 0, stream>>>(feats, mask, trans, out);
}

// Round 3
// 3001.456 us; speedup vs baseline: 7.3822x; 7.3822x over previous
//
#include <hip/hip_runtime.h>

#define SLEN 512
#define BATCH 64
#define HID 256
#define EMB 128
#define NT 18
#define KTOT 384          // 256 (h) + 128 (emb)
#define BQ 16             // batches per group
#define WGS_PER_GROUP 32
#define FB 8              // batches per feats block

typedef unsigned int u32;

__device__ __forceinline__ float sigmoidf_(float v) { return 1.0f / (1.0f + expf(-v)); }

// ---------------------------------------------------------------------------
// Persistent bidirectional LSTM. grid = 256 blocks x 256 threads (1 WG/CU).
// group g = blockIdx%8 : dir = g>>2, batch-chunk = g&3 (16 batches).
// rank rk = blockIdx/8 : owns hidden units [8rk, 8rk+8) -> 32 gate rows.
// Weights in VGPRs (8-way K-split, 48 floats/thread).
//
// Fence-free step exchange:
//   producers : h via relaxed AGENT atomic stores (write-through, sc0sc1)
//               -> s_waitcnt vmcnt(0) per wave -> __syncthreads
//               -> tid0 publishes flags[g][it][rk]=1 (relaxed atomic store)
//   consumers : poll 32 flags with relaxed bypass loads (no invalidates),
//               then read h with relaxed bypass loads (no stale-cache risk).
// No __threadfence, no acquire-in-loop => no buffer_wbl2/buffer_inv storms.
// ---------------------------------------------------------------------------
__global__ __launch_bounds__(256, 1) void lstm_kernel(
    const int* __restrict__ x, const float* __restrict__ embed,
    const float* __restrict__ Wih_f, const float* __restrict__ Whh_f,
    const float* __restrict__ bih_f, const float* __restrict__ bhh_f,
    const float* __restrict__ Wih_b, const float* __restrict__ Whh_b,
    const float* __restrict__ bih_b, const float* __restrict__ bhh_b,
    const float* __restrict__ h0, const float* __restrict__ c0,
    float* __restrict__ h_hist, u32* __restrict__ flags)
{
  const int g   = blockIdx.x & 7;
  const int rk  = blockIdx.x >> 3;
  const int dir = g >> 2;
  const int b0  = (g & 3) * BQ;
  const int tid = threadIdx.x;
  const int kg  = tid >> 5;          // 0..7  (K-split group, 48 k's each)
  const int r   = tid & 31;          // row within WG's 32 gate rows
  const int gi  = r >> 3;            // gate index: 0=i 1=f 2=g 3=o
  const int uo  = r & 7;             // unit offset
  const int grow = gi * 256 + rk * 8 + uo;

  const float* Wih = dir ? Wih_b : Wih_f;
  const float* Whh = dir ? Whh_b : Whh_f;
  const float* bih = dir ? bih_b : bih_f;
  const float* bhh = dir ? bhh_b : bhh_f;

  // persistent weight slice: rows 'grow', k in [48*kg, 48*kg+48)
  float4 wreg[12];
#pragma unroll
  for (int c = 0; c < 12; ++c) {
    int k0 = kg * 48 + c * 4;
    if (k0 < 256) wreg[c] = *(const float4*)(Whh + (size_t)grow * 256 + k0);
    else          wreg[c] = *(const float4*)(Wih + (size_t)grow * 128 + (k0 - 256));
  }

  __shared__ float vlds[BQ][KTOT];   // v = [h_prev (256) | emb (128)]
  __shared__ float red[4][BQ][33];   // cross-wave partial reduction
  __shared__ float cst[BQ][8];       // cell state (persistent)
  __shared__ float bias[32];

  if (tid < 32) {
    int gr2 = (tid >> 3) * 256 + rk * 8 + (tid & 7);
    bias[tid] = bih[gr2] + bhh[gr2];
  }
  if (tid < 128) {
    int b = tid >> 3, u = tid & 7;
    cst[b][u] = c0[(size_t)(dir * BATCH + b0 + b) * HID + rk * 8 + u];
  }

  const int b1 = tid >> 5;          // 0..7
  const int b2 = 8 + (tid >> 5);    // 8..15
  const int e1 = (tid & 31) * 4;    // 0..124

  for (int it = 0; it < SLEN; ++it) {
    const int t = dir ? (SLEN - 1 - it) : it;

    // ---- prefetch x + embed into regs (step-independent, hides under poll)
    int xid1 = x[(b0 + b1) * SLEN + t];
    int xid2 = x[(b0 + b2) * SLEN + t];
    float4 ev1 = *(const float4*)(embed + (size_t)xid1 * EMB + e1);
    float4 ev2 = *(const float4*)(embed + (size_t)xid2 * EMB + e1);

    // ---- wait for previous step's h from all 32 WGs of this group
    if (it > 0) {
      const u32* fl = flags + ((size_t)g * SLEN + (it - 1)) * 32;
      int sp = 0;
      u32 v = __hip_atomic_load((u32*)(fl + (tid & 31)), __ATOMIC_RELAXED,
                                __HIP_MEMORY_SCOPE_AGENT);
      bool ok = __all(v != 0);
      while (!ok && ++sp < (1 << 14)) {
        __builtin_amdgcn_s_sleep(1);
        v = __hip_atomic_load((u32*)(fl + (tid & 31)), __ATOMIC_RELAXED,
                              __HIP_MEMORY_SCOPE_AGENT);
        ok = __all(v != 0);
      }
    }
    asm volatile("" ::: "memory");

    // ---- stage h (bypass loads -> LDS). hs[tid + i*256] => vlds[i][tid]
    u32 htmp[16];
    if (it == 0) {
      const u32* hs = (const u32*)(h0 + (size_t)(dir * BATCH + b0) * HID);
#pragma unroll
      for (int i = 0; i < 16; ++i) htmp[i] = hs[tid + i * 256];
    } else {
      const int tp = dir ? (t + 1) : (t - 1);
      const u32* hs = (const u32*)(h_hist +
                       ((size_t)(dir * SLEN + tp) * BATCH + b0) * HID);
#pragma unroll
      for (int i = 0; i < 16; ++i)
        htmp[i] = __hip_atomic_load((u32*)(hs + tid + i * 256),
                                    __ATOMIC_RELAXED, __HIP_MEMORY_SCOPE_AGENT);
    }
    *(float4*)&vlds[b1][256 + e1] = ev1;
    *(float4*)&vlds[b2][256 + e1] = ev2;
#pragma unroll
    for (int i = 0; i < 16; ++i) *(u32*)&vlds[i][tid] = htmp[i];
    __syncthreads();                                   // SYNC_A

    // ---- K-split GEMM: acc[b] = sum over this thread's 48 k's ----
    float acc[BQ];
#pragma unroll
    for (int b = 0; b < BQ; ++b) acc[b] = 0.0f;
    const int kb = kg * 48;
#pragma unroll
    for (int bb = 0; bb < BQ; bb += 4) {
#pragma unroll
      for (int c = 0; c < 12; ++c) {
        float4 w4 = wreg[c];
#pragma unroll
        for (int q = 0; q < 4; ++q) {
          float4 v4 = *(const float4*)&vlds[bb + q][kb + c * 4];
          float a = acc[bb + q];
          a = fmaf(w4.x, v4.x, a);
          a = fmaf(w4.y, v4.y, a);
          a = fmaf(w4.z, v4.z, a);
          a = fmaf(w4.w, v4.w, a);
          acc[bb + q] = a;
        }
      }
    }

    // ---- reduce the 8 K-partials: in-wave pair, then 4 waves via LDS ----
#pragma unroll
    for (int b = 0; b < BQ; ++b) acc[b] += __shfl_xor(acc[b], 32);
    const int wv = tid >> 6;
    if ((tid & 32) == 0) {
#pragma unroll
      for (int b = 0; b < BQ; ++b) red[wv][b][r] = acc[b];
    }
    __syncthreads();                                   // SYNC_B

    // ---- gates + state update + h publish (write-through stores) ----
    if (tid < 128) {
      int b = tid >> 3, u = tid & 7;
      float gs[4];
#pragma unroll
      for (int gg = 0; gg < 4; ++gg) {
        int rr = gg * 8 + u;
        float s = bias[rr];
#pragma unroll
        for (int w = 0; w < 4; ++w) s += red[w][b][rr];
        gs[gg] = s;
      }
      float ig = sigmoidf_(gs[0]);
      float fg = sigmoidf_(gs[1]);
      float gv = tanhf(gs[2]);
      float og = sigmoidf_(gs[3]);
      float cv = fg * cst[b][u] + ig * gv;
      cst[b][u] = cv;
      float hv = og * tanhf(cv);
      __hip_atomic_store(h_hist + ((size_t)(dir * SLEN + t) * BATCH + (b0 + b)) * HID
                           + rk * 8 + u,
                         hv, __ATOMIC_RELAXED, __HIP_MEMORY_SCOPE_AGENT);
    }

    // per-wave commit, join, publish flag
    asm volatile("s_waitcnt vmcnt(0)" ::: "memory");
    __syncthreads();                                   // SYNC_C
    if (tid == 0)
      __hip_atomic_store(flags + ((size_t)g * SLEN + it) * 32 + rk, 1u,
                         __ATOMIC_RELAXED, __HIP_MEMORY_SCOPE_AGENT);
  }
}

// ---------------------------------------------------------------------------
// feats[s][b][tag] = [hf|hb] . Wc[tag] + bc[tag]
// grid = 512*8 blocks (s, 8-batch chunk), 256 threads. LDS ~54KB.
// ---------------------------------------------------------------------------
__global__ __launch_bounds__(256) void feats_kernel(
    const float* __restrict__ h_hist, const float* __restrict__ Wc,
    const float* __restrict__ bc, float* __restrict__ feats)
{
  const int s   = blockIdx.x >> 3;
  const int b0  = (blockIdx.x & 7) * FB;
  const int tid = threadIdx.x;
  __shared__ float wc[NT * 516];    // 37.2 KB
  __shared__ float hl[FB * 516];    // 16.5 KB
  __shared__ float bcl[NT];
  if (tid < NT) bcl[tid] = bc[tid];
  for (int f = tid * 4; f < NT * 512; f += 1024) {
    float4 v = *(const float4*)(Wc + f);
    *(float4*)&wc[(f >> 9) * 516 + (f & 511)] = v;
  }
  {
    const float* src0 = h_hist + ((size_t)s * BATCH + b0) * HID;
    const float* src1 = h_hist + ((size_t)(SLEN + s) * BATCH + b0) * HID;
    for (int f = tid * 4; f < FB * 256; f += 1024) {
      int b = f >> 8, j = f & 255;
      *(float4*)&hl[b * 516 + j]       = *(const float4*)(src0 + f);
      *(float4*)&hl[b * 516 + 256 + j] = *(const float4*)(src1 + f);
    }
  }
  __syncthreads();
  if (tid < FB * NT) {
    int b = tid / NT, tag = tid - b * NT;
    float a = bcl[tag];
    const float* hp = &hl[b * 516];
    const float* wp = &wc[tag * 516];
#pragma unroll 8
    for (int k = 0; k < 512; k += 4) {
      float4 h4 = *(const float4*)(hp + k);
      float4 w4 = *(const float4*)(wp + k);
      a = fmaf(h4.x, w4.x, a); a = fmaf(h4.y, w4.y, a);
      a = fmaf(h4.z, w4.z, a); a = fmaf(h4.w, w4.w, a);
    }
    feats[((size_t)s * BATCH + b0 + b) * NT + tag] = a;
  }
}

// ---------------------------------------------------------------------------
// Viterbi + backtrace, one block per batch, 64 threads (lanes 0..17 active).
// Replicates reference exactly, including add order:
//   cur = (feats[to] + trans[from][to]) + partition[from];  new_p = max(cur)
// strict > keeps the FIRST max (matches jnp.argmax). Masked bp=0, snapshot at
// t=len-1, back[len-1]=pointer overwrite, decode[S-1]=pointer.
// ---------------------------------------------------------------------------
__global__ __launch_bounds__(64) void viterbi_kernel(
    const float* __restrict__ feats, const int* __restrict__ mask,
    const float* __restrict__ trans, float* __restrict__ out)
{
  const int b = blockIdx.x;
  const int lane = threadIdx.x;
  __shared__ float tr[NT][NT + 1];
  __shared__ float part[2][NT + 2];
  __shared__ float lastp[NT + 2];
  __shared__ unsigned char bp[SLEN][20];
  __shared__ int len_s;

  for (int f = lane; f < NT * NT; f += 64) tr[f / NT][f % NT] = trans[f];
  int m = 0;
#pragma unroll
  for (int i = 0; i < 8; ++i) m += mask[b * SLEN + lane * 8 + i];
  for (int off = 32; off; off >>= 1) m += __shfl_down(m, off);
  if (lane == 0) len_s = m;
  __syncthreads();
  const int len = len_s;

  if (lane < NT) part[0][lane] = feats[(size_t)b * NT + lane] + tr[16][lane];  // START=16
  __syncthreads();

  int cur = 0;
  float fnext = (lane < NT) ? feats[((size_t)BATCH + b) * NT + lane] : 0.0f;
  int   mnext = mask[b * SLEN + 1];
  for (int t = 1; t < SLEN; ++t) {
    float fcur = fnext; int mcur = mnext;
    if (t < SLEN - 1) {
      fnext = (lane < NT) ? feats[((size_t)(t + 1) * BATCH + b) * NT + lane] : 0.0f;
      mnext = mask[b * SLEN + t + 1];
    }
    if (lane < NT) {
      float best = -3.0e38f; int bf = 0;
#pragma unroll
      for (int from = 0; from < NT; ++from) {
        float v = (fcur + tr[from][lane]) + part[cur][from];  // exact ref order
        if (v > best) { best = v; bf = from; }
      }
      part[cur ^ 1][lane] = best;          // new_p includes feats (ref semantics)
      bp[t][lane] = mcur ? (unsigned char)bf : (unsigned char)0;
      if (t == len - 1) lastp[lane] = best;
    }
    cur ^= 1;
    __syncthreads();
  }

  if (lane == 0) {
    float best = -3.0e38f; int bf = 0;
    for (int from = 0; from < NT; ++from) {
      float v = lastp[from] + tr[from][17];      // END=17
      if (v > best) { best = v; bf = from; }
    }
    out[b] = best;                                // path_score
    int ptr = bf;
    out[BATCH + (size_t)b * SLEN + (SLEN - 1)] = (float)ptr;
    for (int i = SLEN - 2; i >= 0; --i) {
      int nw = (i == len - 1) ? bf : (int)bp[i + 1][ptr];
      out[BATCH + (size_t)b * SLEN + i] = (float)nw;
      ptr = nw;
    }
  }
}

// ---------------------------------------------------------------------------
extern "C" void kernel_launch(void* const* d_in, const int* in_sizes, int n_in,
                              void* d_out, int out_size, void* d_ws, size_t ws_size,
                              hipStream_t stream) {
  const int*   x      = (const int*)  d_in[0];
  const int*   mask   = (const int*)  d_in[1];
  const float* embed  = (const float*)d_in[2];
  const float* Wih_f  = (const float*)d_in[3];
  const float* Whh_f  = (const float*)d_in[4];
  const float* bih_f  = (const float*)d_in[5];
  const float* bhh_f  = (const float*)d_in[6];
  const float* Wih_b  = (const float*)d_in[7];
  const float* Whh_b  = (const float*)d_in[8];
  const float* bih_b  = (const float*)d_in[9];
  const float* bhh_b  = (const float*)d_in[10];
  const float* Wc     = (const float*)d_in[11];
  const float* bc     = (const float*)d_in[12];
  const float* trans  = (const float*)d_in[13];
  const float* h0     = (const float*)d_in[14];
  const float* c0     = (const float*)d_in[15];
  float* out = (float*)d_out;

  // ws layout: h_hist @0 (64MB); flags and feats SHARE ws+64MB (disjoint in
  // time: flags used only during lstm, feats written only after lstm).
  char* ws = (char*)d_ws;
  float* h_hist = (float*)ws;                                 // 2*512*64*256*4 = 64 MB
  u32*   flags  = (u32*)(ws + (size_t)67108864);              // 8*512*32*4 = 512 KB
  float* feats  = (float*)(ws + (size_t)67108864);            // 512*64*18*4 = 2.25 MB

  hipMemsetAsync(flags, 0, 8 * SLEN * WGS_PER_GROUP * sizeof(u32), stream);
  lstm_kernel<<<256, 256, 0, stream>>>(x, embed, Wih_f, Whh_f, bih_f, bhh_f,
                                       Wih_b, Whh_b, bih_b, bhh_b, h0, c0,
                                       h_hist, flags);
  feats_kernel<<<SLEN * 8, 256, 0, stream>>>(h_hist, Wc, bc, feats);
  viterbi_kernel<<<BATCH, 64, 0, stream>>>(feats, mask, trans, out);
}

// Round 4
// 2735.187 us; speedup vs baseline: 8.1009x; 1.0973x over previous
//
#include <hip/hip_runtime.h>

#define SLEN 512
#define BATCH 64
#define HID 256
#define EMB 128
#define NT 18
#define KTOT 384          // 256 (h) + 128 (emb)
#define BQ 8              // batches per group
#define NGROUP 16         // 2 dirs x 8 batch-chunks
#define NSLICE 32         // producer WGs per group
#define FB 8              // batches per feats block

typedef unsigned int u32;

__device__ __forceinline__ float sigmoidf_(float v) { return 1.0f / (1.0f + expf(-v)); }

// ---------------------------------------------------------------------------
// Persistent bidirectional LSTM. grid = 512 blocks x 256 threads, 2 blocks/CU
// (forced by LDS pad -> exactly 2 per CU by capacity; all co-resident).
// group g = blockIdx&15 : dir = g>>3, batch-chunk = g&7 (8 batches).
// slice rk = blockIdx>>4 (0..31): hidden units [8rk,8rk+8) -> 32 gate rows.
// Weights in VGPRs (8-way K-split, 48 floats/thread).
//
// Per-step wave roles:
//   wave0 : GEMM + gates + h stores (write-through) + vmcnt(0) + flag publish
//   wave1 : GEMM + sole global poller of 32 flags -> LDS `ready` relay
//   waves 2,3 : GEMM only; spin on LDS `ready` (no global poll traffic)
// Two co-resident blocks per CU hide each other's exchange latency.
// ---------------------------------------------------------------------------
__global__ __launch_bounds__(256, 2) void lstm_kernel(
    const int* __restrict__ x, const float* __restrict__ embed,
    const float* __restrict__ Wih_f, const float* __restrict__ Whh_f,
    const float* __restrict__ bih_f, const float* __restrict__ bhh_f,
    const float* __restrict__ Wih_b, const float* __restrict__ Whh_b,
    const float* __restrict__ bih_b, const float* __restrict__ bhh_b,
    const float* __restrict__ h0, const float* __restrict__ c0,
    float* __restrict__ h_hist, u32* __restrict__ flags)
{
  const int g   = blockIdx.x & 15;
  const int rk  = blockIdx.x >> 4;   // 0..31
  const int dir = g >> 3;
  const int b0  = (g & 7) * BQ;
  const int tid = threadIdx.x;
  const int kg  = tid >> 5;          // 0..7  (K-split group, 48 k's each)
  const int r   = tid & 31;          // row within the 32 gate rows
  const int gi  = r >> 3;            // gate index: 0=i 1=f 2=g 3=o
  const int uo  = r & 7;             // unit offset
  const int grow = gi * 256 + rk * 8 + uo;

  const float* Wih = dir ? Wih_b : Wih_f;
  const float* Whh = dir ? Whh_b : Whh_f;
  const float* bih = dir ? bih_b : bih_f;
  const float* bhh = dir ? bhh_b : bhh_f;

  // persistent weight slice: row 'grow', k in [48*kg, 48*kg+48)
  float4 wreg[12];
#pragma unroll
  for (int c = 0; c < 12; ++c) {
    int k0 = kg * 48 + c * 4;
    if (k0 < 256) wreg[c] = *(const float4*)(Whh + (size_t)grow * 256 + k0);
    else          wreg[c] = *(const float4*)(Wih + (size_t)grow * 128 + (k0 - 256));
  }

  __shared__ float vlds[BQ][KTOT];   // 12 KB : v = [h_prev (256) | emb (128)]
  __shared__ float red[4][BQ][33];   // 4.2 KB : cross-wave partial reduction
  __shared__ float cst[BQ][8];       // cell state (persistent)
  __shared__ float bias[32];
  __shared__ u32   ready;            // LDS relay: last step whose flags are confirmed
  __shared__ float ldspad[10624];    // 42.5 KB pad -> LDS ~58 KB -> max 2 blocks/CU

  if (x == nullptr) ((volatile float*)ldspad)[0] = 1.0f;  // keep pad allocated

  if (tid < 32) bias[tid] = bih[grow] + bhh[grow];
  if (tid < 64) {
    int b = tid >> 3, u = tid & 7;
    cst[b][u] = c0[(size_t)(dir * BATCH + b0 + b) * HID + rk * 8 + u];
  }
  if (tid == 0) ready = 0;
  __syncthreads();

  const int b1 = tid >> 5;           // 0..7 (batch for emb staging)
  const int e1 = (tid & 31) * 4;     // 0..124
  const int wv = tid >> 6;           // wave id 0..3

  for (int it = 0; it < SLEN; ++it) {
    const int t = dir ? (SLEN - 1 - it) : it;

    // ---- prefetch x + embed (step-independent; hides under poll) ----
    int xid = x[(b0 + b1) * SLEN + t];
    float4 ev = *(const float4*)(embed + (size_t)xid * EMB + e1);

    // ---- wait for previous step's h from all 32 WGs of this group ----
    if (it > 0) {
      if (wv == 1) {
        const u32* fl = flags + ((size_t)g * SLEN + (it - 1)) * NSLICE + (tid & 31);
        int sp = 0;
        u32 v = __hip_atomic_load((u32*)fl, __ATOMIC_RELAXED, __HIP_MEMORY_SCOPE_AGENT);
        while (!__all(v != 0) && ++sp < (1 << 12)) {
          __builtin_amdgcn_s_sleep(2);
          v = __hip_atomic_load((u32*)fl, __ATOMIC_RELAXED, __HIP_MEMORY_SCOPE_AGENT);
        }
        if (tid == 64) *((volatile u32*)&ready) = (u32)it;
      } else {
        int sp = 0;
        while (*((volatile u32*)&ready) < (u32)it && ++sp < (1 << 20))
          __builtin_amdgcn_s_sleep(1);
      }
    }
    asm volatile("" ::: "memory");

    // ---- stage h (bypass loads) + emb into LDS ----
    u32 htmp[BQ];
    if (it == 0) {
      const u32* hs = (const u32*)(h0 + (size_t)(dir * BATCH + b0) * HID);
#pragma unroll
      for (int i = 0; i < BQ; ++i) htmp[i] = hs[tid + i * 256];
    } else {
      const int tp = dir ? (t + 1) : (t - 1);
      const u32* hs = (const u32*)(h_hist +
                       ((size_t)(dir * SLEN + tp) * BATCH + b0) * HID);
#pragma unroll
      for (int i = 0; i < BQ; ++i)
        htmp[i] = __hip_atomic_load((u32*)(hs + tid + i * 256),
                                    __ATOMIC_RELAXED, __HIP_MEMORY_SCOPE_AGENT);
    }
    *(float4*)&vlds[b1][256 + e1] = ev;
#pragma unroll
    for (int i = 0; i < BQ; ++i) *(u32*)&vlds[i][tid] = htmp[i];
    __syncthreads();                                   // SYNC_A

    // ---- K-split GEMM: acc[b] over this thread's 48 k's ----
    float acc[BQ];
#pragma unroll
    for (int b = 0; b < BQ; ++b) acc[b] = 0.0f;
    const int kb = kg * 48;
#pragma unroll
    for (int c = 0; c < 12; ++c) {
      float4 w4 = wreg[c];
#pragma unroll
      for (int q = 0; q < BQ; ++q) {
        float4 v4 = *(const float4*)&vlds[q][kb + c * 4];
        float a = acc[q];
        a = fmaf(w4.x, v4.x, a);
        a = fmaf(w4.y, v4.y, a);
        a = fmaf(w4.z, v4.z, a);
        a = fmaf(w4.w, v4.w, a);
        acc[q] = a;
      }
    }

    // ---- reduce 8 K-partials: in-wave pair, then 4 waves via LDS ----
#pragma unroll
    for (int b = 0; b < BQ; ++b) acc[b] += __shfl_xor(acc[b], 32);
    if ((tid & 32) == 0) {
#pragma unroll
      for (int b = 0; b < BQ; ++b) red[wv][b][r] = acc[b];
    }
    __syncthreads();                                   // SYNC_B

    // ---- gates + state update + h publish (wave0 only) ----
    if (tid < 64) {
      int b = tid >> 3, u = tid & 7;
      float gs[4];
#pragma unroll
      for (int gg = 0; gg < 4; ++gg) {
        int rr = gg * 8 + u;
        float s = bias[rr];
#pragma unroll
        for (int w = 0; w < 4; ++w) s += red[w][b][rr];
        gs[gg] = s;
      }
      float ig = sigmoidf_(gs[0]);
      float fg = sigmoidf_(gs[1]);
      float gv = tanhf(gs[2]);
      float og = sigmoidf_(gs[3]);
      float cv = fg * cst[b][u] + ig * gv;
      cst[b][u] = cv;
      float hv = og * tanhf(cv);
      __hip_atomic_store(h_hist + ((size_t)(dir * SLEN + t) * BATCH + (b0 + b)) * HID
                           + rk * 8 + u,
                         hv, __ATOMIC_RELAXED, __HIP_MEMORY_SCOPE_AGENT);
    }
    asm volatile("s_waitcnt vmcnt(0)" ::: "memory");    // wave0: h committed
    if (tid == 0)
      __hip_atomic_store(flags + ((size_t)g * SLEN + it) * NSLICE + rk, 1u,
                         __ATOMIC_RELAXED, __HIP_MEMORY_SCOPE_AGENT);
    // waves 1-3 proceed directly to next step's prefetch/poll (no barrier);
    // red/vlds WAR safety: next-step writes happen only after SYNC_A(it+1),
    // which wave0 reaches only after gates read `red`.
  }
}

// ---------------------------------------------------------------------------
// feats[s][b][tag] = [hf|hb] . Wc[tag] + bc[tag]
// grid = 512*8 blocks (s, 8-batch chunk), 256 threads. LDS ~54KB.
// ---------------------------------------------------------------------------
__global__ __launch_bounds__(256) void feats_kernel(
    const float* __restrict__ h_hist, const float* __restrict__ Wc,
    const float* __restrict__ bc, float* __restrict__ feats)
{
  const int s   = blockIdx.x >> 3;
  const int b0  = (blockIdx.x & 7) * FB;
  const int tid = threadIdx.x;
  __shared__ float wc[NT * 516];    // 37.2 KB
  __shared__ float hl[FB * 516];    // 16.5 KB
  __shared__ float bcl[NT];
  if (tid < NT) bcl[tid] = bc[tid];
  for (int f = tid * 4; f < NT * 512; f += 1024) {
    float4 v = *(const float4*)(Wc + f);
    *(float4*)&wc[(f >> 9) * 516 + (f & 511)] = v;
  }
  {
    const float* src0 = h_hist + ((size_t)s * BATCH + b0) * HID;
    const float* src1 = h_hist + ((size_t)(SLEN + s) * BATCH + b0) * HID;
    for (int f = tid * 4; f < FB * 256; f += 1024) {
      int b = f >> 8, j = f & 255;
      *(float4*)&hl[b * 516 + j]       = *(const float4*)(src0 + f);
      *(float4*)&hl[b * 516 + 256 + j] = *(const float4*)(src1 + f);
    }
  }
  __syncthreads();
  if (tid < FB * NT) {
    int b = tid / NT, tag = tid - b * NT;
    float a = bcl[tag];
    const float* hp = &hl[b * 516];
    const float* wp = &wc[tag * 516];
#pragma unroll 8
    for (int k = 0; k < 512; k += 4) {
      float4 h4 = *(const float4*)(hp + k);
      float4 w4 = *(const float4*)(wp + k);
      a = fmaf(h4.x, w4.x, a); a = fmaf(h4.y, w4.y, a);
      a = fmaf(h4.z, w4.z, a); a = fmaf(h4.w, w4.w, a);
    }
    feats[((size_t)s * BATCH + b0 + b) * NT + tag] = a;
  }
}

// ---------------------------------------------------------------------------
// Viterbi + backtrace, one block per batch, 64 threads (lanes 0..17 active).
// Replicates reference exactly, including add order:
//   cur = (feats[to] + trans[from][to]) + partition[from];  new_p = max(cur)
// strict > keeps the FIRST max (matches jnp.argmax). Masked bp=0, snapshot at
// t=len-1, back[len-1]=pointer overwrite, decode[S-1]=pointer.
// ---------------------------------------------------------------------------
__global__ __launch_bounds__(64) void viterbi_kernel(
    const float* __restrict__ feats, const int* __restrict__ mask,
    const float* __restrict__ trans, float* __restrict__ out)
{
  const int b = blockIdx.x;
  const int lane = threadIdx.x;
  __shared__ float tr[NT][NT + 1];
  __shared__ float part[2][NT + 2];
  __shared__ float lastp[NT + 2];
  __shared__ unsigned char bp[SLEN][20];
  __shared__ int len_s;

  for (int f = lane; f < NT * NT; f += 64) tr[f / NT][f % NT] = trans[f];
  int m = 0;
#pragma unroll
  for (int i = 0; i < 8; ++i) m += mask[b * SLEN + lane * 8 + i];
  for (int off = 32; off; off >>= 1) m += __shfl_down(m, off);
  if (lane == 0) len_s = m;
  __syncthreads();
  const int len = len_s;

  if (lane < NT) part[0][lane] = feats[(size_t)b * NT + lane] + tr[16][lane];  // START=16
  __syncthreads();

  int cur = 0;
  float fnext = (lane < NT) ? feats[((size_t)BATCH + b) * NT + lane] : 0.0f;
  int   mnext = mask[b * SLEN + 1];
  for (int t = 1; t < SLEN; ++t) {
    float fcur = fnext; int mcur = mnext;
    if (t < SLEN - 1) {
      fnext = (lane < NT) ? feats[((size_t)(t + 1) * BATCH + b) * NT + lane] : 0.0f;
      mnext = mask[b * SLEN + t + 1];
    }
    if (lane < NT) {
      float best = -3.0e38f; int bf = 0;
#pragma unroll
      for (int from = 0; from < NT; ++from) {
        float v = (fcur + tr[from][lane]) + part[cur][from];  // exact ref order
        if (v > best) { best = v; bf = from; }
      }
      part[cur ^ 1][lane] = best;          // new_p includes feats (ref semantics)
      bp[t][lane] = mcur ? (unsigned char)bf : (unsigned char)0;
      if (t == len - 1) lastp[lane] = best;
    }
    cur ^= 1;
    __syncthreads();
  }

  if (lane == 0) {
    float best = -3.0e38f; int bf = 0;
    for (int from = 0; from < NT; ++from) {
      float v = lastp[from] + tr[from][17];      // END=17
      if (v > best) { best = v; bf = from; }
    }
    out[b] = best;                                // path_score
    int ptr = bf;
    out[BATCH + (size_t)b * SLEN + (SLEN - 1)] = (float)ptr;
    for (int i = SLEN - 2; i >= 0; --i) {
      int nw = (i == len - 1) ? bf : (int)bp[i + 1][ptr];
      out[BATCH + (size_t)b * SLEN + i] = (float)nw;
      ptr = nw;
    }
  }
}

// ---------------------------------------------------------------------------
extern "C" void kernel_launch(void* const* d_in, const int* in_sizes, int n_in,
                              void* d_out, int out_size, void* d_ws, size_t ws_size,
                              hipStream_t stream) {
  const int*   x      = (const int*)  d_in[0];
  const int*   mask   = (const int*)  d_in[1];
  const float* embed  = (const float*)d_in[2];
  const float* Wih_f  = (const float*)d_in[3];
  const float* Whh_f  = (const float*)d_in[4];
  const float* bih_f  = (const float*)d_in[5];
  const float* bhh_f  = (const float*)d_in[6];
  const float* Wih_b  = (const float*)d_in[7];
  const float* Whh_b  = (const float*)d_in[8];
  const float* bih_b  = (const float*)d_in[9];
  const float* bhh_b  = (const float*)d_in[10];
  const float* Wc     = (const float*)d_in[11];
  const float* bc     = (const float*)d_in[12];
  const float* trans  = (const float*)d_in[13];
  const float* h0     = (const float*)d_in[14];
  const float* c0     = (const float*)d_in[15];
  float* out = (float*)d_out;

  // ws layout: h_hist @0 (64MB); flags and feats SHARE ws+64MB (disjoint in
  // time: flags used only during lstm, feats written only after lstm).
  char* ws = (char*)d_ws;
  float* h_hist = (float*)ws;                                 // 64 MB
  u32*   flags  = (u32*)(ws + (size_t)67108864);              // 16*512*32*4 = 1 MB
  float* feats  = (float*)(ws + (size_t)67108864);            // 2.25 MB (aliases flags)

  hipMemsetAsync(flags, 0, (size_t)NGROUP * SLEN * NSLICE * sizeof(u32), stream);
  lstm_kernel<<<512, 256, 0, stream>>>(x, embed, Wih_f, Whh_f, bih_f, bhh_f,
                                       Wih_b, Whh_b, bih_b, bhh_b, h0, c0,
                                       h_hist, flags);
  feats_kernel<<<SLEN * 8, 256, 0, stream>>>(h_hist, Wc, bc, feats);
  viterbi_kernel<<<BATCH, 64, 0, stream>>>(feats, mask, trans, out);
}